// Round 1
// baseline (1700.409 us; speedup 1.0000x reference)
//
#include <hip/hip_runtime.h>
#include <float.h>
#include <math.h>

#define D 1024
#define BQ 256
#define NMEM 100000
#define TOPK 16
#define CH 192
#define NCHUNK 521               // ceil(100000/192); covers [0,100032)
#define CAND (NCHUNK * TOPK)     // 8336 candidates per query row

// ---------------- reductions ----------------

__device__ __forceinline__ float waveReduceSum(float v) {
#pragma unroll
  for (int o = 32; o > 0; o >>= 1) v += __shfl_xor(v, o, 64);
  return v;
}

__device__ __forceinline__ float blockReduceSum(float v, float* sbuf) {
  v = waveReduceSum(v);
  int w = threadIdx.x >> 6;
  if ((threadIdx.x & 63) == 0) sbuf[w] = v;
  __syncthreads();
  float r = sbuf[0] + sbuf[1] + sbuf[2] + sbuf[3];
  __syncthreads();
  return r;
}

// ---------------- small GEMM: C[m][n] = sum_k A[m][k]*W[n][k] + bias[n] ----
// M=256, N=1024, K=1024. Tile 32x64, 256 threads, 2x4 micro-tile.

__global__ __launch_bounds__(256) void gemm_bias_kernel(
    const float* __restrict__ A, const float* __restrict__ W,
    const float* __restrict__ bias, float* __restrict__ C) {
  __shared__ float As[32][33];
  __shared__ float Bs[64][33];
  int t = threadIdx.x;
  int tx = t & 15, ty = t >> 4;
  int rowBase = blockIdx.y * 32;
  int colBase = blockIdx.x * 64;
  float acc[2][4] = {};
  for (int kb = 0; kb < D; kb += 32) {
    {
      int r = t >> 3, k4 = (t & 7) * 4;
      float4 v = *(const float4*)(A + (size_t)(rowBase + r) * D + kb + k4);
      As[r][k4 + 0] = v.x; As[r][k4 + 1] = v.y; As[r][k4 + 2] = v.z; As[r][k4 + 3] = v.w;
    }
#pragma unroll
    for (int u = 0; u < 2; ++u) {
      int q = t + 256 * u;
      int r = q >> 3, k4 = (q & 7) * 4;
      float4 v = *(const float4*)(W + (size_t)(colBase + r) * D + kb + k4);
      Bs[r][k4 + 0] = v.x; Bs[r][k4 + 1] = v.y; Bs[r][k4 + 2] = v.z; Bs[r][k4 + 3] = v.w;
    }
    __syncthreads();
#pragma unroll 8
    for (int kk = 0; kk < 32; ++kk) {
      float b0 = Bs[tx * 4 + 0][kk], b1 = Bs[tx * 4 + 1][kk];
      float b2 = Bs[tx * 4 + 2][kk], b3 = Bs[tx * 4 + 3][kk];
#pragma unroll
      for (int i = 0; i < 2; ++i) {
        float a = As[ty * 2 + i][kk];
        acc[i][0] = fmaf(a, b0, acc[i][0]);
        acc[i][1] = fmaf(a, b1, acc[i][1]);
        acc[i][2] = fmaf(a, b2, acc[i][2]);
        acc[i][3] = fmaf(a, b3, acc[i][3]);
      }
    }
    __syncthreads();
  }
#pragma unroll
  for (int i = 0; i < 2; ++i) {
    int m = rowBase + ty * 2 + i;
#pragma unroll
    for (int j = 0; j < 4; ++j) {
      int n = colBase + tx * 4 + j;
      C[(size_t)m * D + n] = acc[i][j] + bias[n];
    }
  }
}

// ---------------- LayerNorm + exact GELU (in place, one row per block) -----

__global__ __launch_bounds__(256) void ln_gelu_kernel(float* __restrict__ h,
                                                      const float* __restrict__ g,
                                                      const float* __restrict__ b) {
  __shared__ float sbuf[4];
  int row = blockIdx.x, t = threadIdx.x;
  float* p = h + (size_t)row * D + t * 4;
  float4 x = *(float4*)p;
  float s = x.x + x.y + x.z + x.w;
  s = blockReduceSum(s, sbuf);
  float mu = s * (1.0f / D);
  float dx = x.x - mu, dy = x.y - mu, dz = x.z - mu, dw = x.w - mu;
  float ss = dx * dx + dy * dy + dz * dz + dw * dw;
  ss = blockReduceSum(ss, sbuf);
  float rstd = rsqrtf(ss * (1.0f / D) + 1e-5f);
  float4 gg = *(const float4*)(g + t * 4);
  float4 bb = *(const float4*)(b + t * 4);
  float y0 = dx * rstd * gg.x + bb.x;
  float y1 = dy * rstd * gg.y + bb.y;
  float y2 = dz * rstd * gg.z + bb.z;
  float y3 = dw * rstd * gg.w + bb.w;
  const float c = 0.70710678118654752f;
  y0 = 0.5f * y0 * (1.0f + erff(y0 * c));
  y1 = 0.5f * y1 * (1.0f + erff(y1 * c));
  y2 = 0.5f * y2 * (1.0f + erff(y2 * c));
  y3 = 0.5f * y3 * (1.0f + erff(y3 * c));
  float4 y = make_float4(y0, y1, y2, y3);
  *(float4*)p = y;
}

// ---------------- L2 normalize rows of r; write to ws (in place) + d_out ---

__global__ __launch_bounds__(256) void l2norm_kernel(float* __restrict__ r,
                                                     float* __restrict__ outRef) {
  __shared__ float sbuf[4];
  int row = blockIdx.x, t = threadIdx.x;
  float* p = r + (size_t)row * D + t * 4;
  float4 x = *(float4*)p;
  float ss = x.x * x.x + x.y * x.y + x.z * x.z + x.w * x.w;
  ss = blockReduceSum(ss, sbuf);
  float inv = 1.0f / fmaxf(sqrtf(ss), 1e-12f);
  x.x *= inv; x.y *= inv; x.z *= inv; x.w *= inv;
  *(float4*)p = x;
  *(float4*)(outRef + (size_t)row * D + t * 4) = x;
}

// ---------------- memory bank inverse norms (wave per row) -----------------

__global__ __launch_bounds__(256) void memnorm_kernel(const float* __restrict__ mem,
                                                      float* __restrict__ inv) {
  int row = blockIdx.x * 4 + (threadIdx.x >> 6);
  int lane = threadIdx.x & 63;
  const float* p = mem + (size_t)row * D;
  float ss = 0.f;
#pragma unroll
  for (int u = 0; u < 4; ++u) {
    float4 v = *(const float4*)(p + lane * 4 + u * 256);
    ss += v.x * v.x + v.y * v.y + v.z * v.z + v.w * v.w;
  }
  ss = waveReduceSum(ss);
  if (lane == 0) inv[row] = 1.0f / fmaxf(sqrtf(ss), 1e-12f);
}

// ---------------- sims GEMM (256 x chunk) + per-row running top-16 ---------
// Block g owns memory rows [g*CH, g*CH+CH). 3 subtiles of 64 cols.
// 256 threads as 16x16; thread computes 16 rows x 4 cols.
// After each subtile: transpose 16-col pieces through LDS so thread t owns
// query-row t's candidates; maintain top-16 in registers (static indices).

__global__ __launch_bounds__(256) void sims_topk_kernel(
    const float* __restrict__ Aref, const float* __restrict__ mem,
    const float* __restrict__ invn, float* __restrict__ cand_v,
    int* __restrict__ cand_i) {
  __shared__ float As[256][33];
  __shared__ float Bs[64][33];
  __shared__ float Pc[256][17];
  int t = threadIdx.x;
  int tx = t & 15, ty = t >> 4;
  int n0 = blockIdx.x * CH;

  float tv[16];
  int ti[16];
#pragma unroll
  for (int s = 0; s < 16; ++s) { tv[s] = -FLT_MAX; ti[s] = 2147483647; }
  float curMin = -FLT_MAX;

  for (int s3 = 0; s3 < 3; ++s3) {
    int nb = n0 + s3 * 64;
    float acc[16][4] = {};
    for (int kb = 0; kb < D; kb += 32) {
#pragma unroll
      for (int u = 0; u < 8; ++u) {
        int q = t + 256 * u;
        int r = q >> 3, k4 = (q & 7) * 4;
        float4 v = *(const float4*)(Aref + (size_t)r * D + kb + k4);
        As[r][k4 + 0] = v.x; As[r][k4 + 1] = v.y; As[r][k4 + 2] = v.z; As[r][k4 + 3] = v.w;
      }
#pragma unroll
      for (int u = 0; u < 2; ++u) {
        int q = t + 256 * u;
        int r = q >> 3, k4 = (q & 7) * 4;
        int n = nb + r;
        float4 v = make_float4(0.f, 0.f, 0.f, 0.f);
        if (n < NMEM) v = *(const float4*)(mem + (size_t)n * D + kb + k4);
        Bs[r][k4 + 0] = v.x; Bs[r][k4 + 1] = v.y; Bs[r][k4 + 2] = v.z; Bs[r][k4 + 3] = v.w;
      }
      __syncthreads();
#pragma unroll 4
      for (int kk = 0; kk < 32; ++kk) {
        float b0 = Bs[tx * 4 + 0][kk], b1 = Bs[tx * 4 + 1][kk];
        float b2 = Bs[tx * 4 + 2][kk], b3 = Bs[tx * 4 + 3][kk];
#pragma unroll
        for (int i = 0; i < 16; ++i) {
          float a = As[ty * 16 + i][kk];
          acc[i][0] = fmaf(a, b0, acc[i][0]);
          acc[i][1] = fmaf(a, b1, acc[i][1]);
          acc[i][2] = fmaf(a, b2, acc[i][2]);
          acc[i][3] = fmaf(a, b3, acc[i][3]);
        }
      }
      __syncthreads();
    }
    // per-row top-16 update, 4 groups of 16 columns
#pragma unroll
    for (int g = 0; g < 4; ++g) {
      if ((tx >> 2) == g) {
#pragma unroll
        for (int i = 0; i < 16; ++i)
#pragma unroll
          for (int j = 0; j < 4; ++j)
            Pc[ty * 16 + i][(tx & 3) * 4 + j] = acc[i][j];
      }
      __syncthreads();
      int nbase = nb + g * 16;
#pragma unroll
      for (int cl = 0; cl < 16; ++cl) {
        int n = nbase + cl;
        if (n < NMEM) {
          float v = Pc[t][cl] * invn[n];
          if (v > curMin) {
            int ms = 0;
            float mv = tv[0];
#pragma unroll
            for (int s = 1; s < 16; ++s)
              if (tv[s] < mv) { mv = tv[s]; ms = s; }
#pragma unroll
            for (int s = 0; s < 16; ++s)
              if (s == ms) { tv[s] = v; ti[s] = n; }
            curMin = tv[0];
#pragma unroll
            for (int s = 1; s < 16; ++s) curMin = fminf(curMin, tv[s]);
          }
        }
      }
      __syncthreads();
    }
  }
  // thread t == query row t
  float* cv = cand_v + (size_t)t * CAND + (size_t)blockIdx.x * 16;
  int* ci = cand_i + (size_t)t * CAND + (size_t)blockIdx.x * 16;
#pragma unroll
  for (int s = 0; s < 16; ++s) { cv[s] = tv[s]; ci[s] = ti[s]; }
}

// ---------------- merge per-chunk top-16s (tie-aware, stable) --------------

__global__ __launch_bounds__(256) void topk_merge_kernel(
    const float* __restrict__ cand_v, const int* __restrict__ cand_i,
    float* __restrict__ out_vals, float* __restrict__ out_idx) {
  __shared__ float rv[256];
  __shared__ int ri[256];
  int b = blockIdx.x, t = threadIdx.x;
  const float* cv = cand_v + (size_t)b * CAND;
  const int* ci = cand_i + (size_t)b * CAND;
  float lastV = FLT_MAX;
  int lastI = -1;
  for (int pass = 0; pass < TOPK; ++pass) {
    float bv = -FLT_MAX;
    int bi = 2147483647;
    for (int p = t; p < CAND; p += 256) {
      float v = cv[p];
      int idx = ci[p];
      bool qual = (v < lastV) || (v == lastV && idx > lastI);
      bool better = (v > bv) || (v == bv && idx < bi);
      if (qual && better) { bv = v; bi = idx; }
    }
    rv[t] = bv; ri[t] = bi;
    __syncthreads();
    for (int off = 128; off > 0; off >>= 1) {
      if (t < off) {
        float v2 = rv[t + off];
        int i2 = ri[t + off];
        if (v2 > rv[t] || (v2 == rv[t] && i2 < ri[t])) { rv[t] = v2; ri[t] = i2; }
      }
      __syncthreads();
    }
    lastV = rv[0];
    lastI = ri[0];
    if (t == 0) {
      out_vals[b * TOPK + pass] = lastV;
      out_idx[b * TOPK + pass] = (float)lastI;
    }
    __syncthreads();
  }
}

// ---------------- gather retrieved = mem_n[topk_idx] -----------------------

__global__ __launch_bounds__(256) void gather_kernel(
    const float* __restrict__ out_idx, const float* __restrict__ mem,
    const float* __restrict__ invn, float* __restrict__ out_retr) {
  int p = blockIdx.x;  // 0..4095 = b*16+j
  int idx = (int)out_idx[p];
  float inv = invn[idx];
  int c = threadIdx.x * 4;
  float4 v = *(const float4*)(mem + (size_t)idx * D + c);
  v.x *= inv; v.y *= inv; v.z *= inv; v.w *= inv;
  *(float4*)(out_retr + (size_t)p * D + c) = v;
}

// ---------------- launch ---------------------------------------------------

extern "C" void kernel_launch(void* const* d_in, const int* in_sizes, int n_in,
                              void* d_out, int out_size, void* d_ws, size_t ws_size,
                              hipStream_t stream) {
  const float* query = (const float*)d_in[0];
  const float* W1 = (const float*)d_in[1];
  const float* b1 = (const float*)d_in[2];
  const float* ln_g = (const float*)d_in[3];
  const float* ln_b = (const float*)d_in[4];
  const float* W2 = (const float*)d_in[5];
  const float* b2 = (const float*)d_in[6];
  const float* mem = (const float*)d_in[7];

  float* out = (float*)d_out;
  float* out_refined = out;                    // 256*1024 = 262144
  float* out_vals = out + 262144;              // 4096
  float* out_idx = out + 262144 + 4096;        // 4096
  float* out_retr = out + 262144 + 8192;       // 256*16*1024

  float* w = (float*)d_ws;
  float* h = w;                                // 262144
  float* r = w + 262144;                       // 262144 (becomes refined)
  float* invn = w + 524288;                    // 100000 (padded to 100352)
  float* cand_v = w + 624640;                  // 521*256*16 = 2134016
  int* cand_i = (int*)(w + 624640 + 2134016);  // 2134016

  gemm_bias_kernel<<<dim3(16, 8), 256, 0, stream>>>(query, W1, b1, h);
  ln_gelu_kernel<<<BQ, 256, 0, stream>>>(h, ln_g, ln_b);
  gemm_bias_kernel<<<dim3(16, 8), 256, 0, stream>>>(h, W2, b2, r);
  l2norm_kernel<<<BQ, 256, 0, stream>>>(r, out_refined);
  memnorm_kernel<<<NMEM / 4, 256, 0, stream>>>(mem, invn);
  sims_topk_kernel<<<NCHUNK, 256, 0, stream>>>(r, mem, invn, cand_v, cand_i);
  topk_merge_kernel<<<BQ, 256, 0, stream>>>(cand_v, cand_i, out_vals, out_idx);
  gather_kernel<<<BQ * TOPK, 256, 0, stream>>>(out_idx, mem, invn, out_retr);
}

// Round 2
// 566.723 us; speedup vs baseline: 3.0004x; 3.0004x over previous
//
#include <hip/hip_runtime.h>
#include <hip/hip_fp16.h>
#include <float.h>
#include <math.h>

#define D 1024
#define BQ 256
#define NMEM 100000
#define TOPK 16
#define CH 256
#define NCHUNK 391               // ceil(100000/256); covers [0,100096)
#define CAND (NCHUNK * TOPK)     // 6256 candidates per query row

typedef __attribute__((ext_vector_type(4))) float f32x4;
typedef __attribute__((ext_vector_type(8))) short s16x8;

__device__ __forceinline__ void mfma16(f32x4& d, s16x8 a, s16x8 b) {
  asm("v_mfma_f32_16x16x32_f16 %0, %1, %2, %0" : "+v"(d) : "v"(a), "v"(b));
}

typedef __attribute__((address_space(3))) unsigned int lds_u32_t;
typedef __attribute__((address_space(1))) const unsigned int gbl_u32_t;
__device__ __forceinline__ void async_copy16(const void* gsrc, void* ldst) {
  __builtin_amdgcn_global_load_lds((gbl_u32_t*)gsrc, (lds_u32_t*)ldst, 16, 0, 0);
}

// ---------------- reductions ----------------

__device__ __forceinline__ float waveReduceSum(float v) {
#pragma unroll
  for (int o = 32; o > 0; o >>= 1) v += __shfl_xor(v, o, 64);
  return v;
}

__device__ __forceinline__ float blockReduceSum(float v, float* sbuf) {
  v = waveReduceSum(v);
  int w = threadIdx.x >> 6;
  if ((threadIdx.x & 63) == 0) sbuf[w] = v;
  __syncthreads();
  float r = sbuf[0] + sbuf[1] + sbuf[2] + sbuf[3];
  __syncthreads();
  return r;
}

// ---------------- small GEMM: C[m][n] = sum_k A[m][k]*W[n][k] + bias[n] ----

__global__ __launch_bounds__(256) void gemm_bias_kernel(
    const float* __restrict__ A, const float* __restrict__ W,
    const float* __restrict__ bias, float* __restrict__ C) {
  __shared__ float As[32][33];
  __shared__ float Bs[64][33];
  int t = threadIdx.x;
  int tx = t & 15, ty = t >> 4;
  int rowBase = blockIdx.y * 32;
  int colBase = blockIdx.x * 64;
  float acc[2][4] = {};
  for (int kb = 0; kb < D; kb += 32) {
    {
      int r = t >> 3, k4 = (t & 7) * 4;
      float4 v = *(const float4*)(A + (size_t)(rowBase + r) * D + kb + k4);
      As[r][k4 + 0] = v.x; As[r][k4 + 1] = v.y; As[r][k4 + 2] = v.z; As[r][k4 + 3] = v.w;
    }
#pragma unroll
    for (int u = 0; u < 2; ++u) {
      int q = t + 256 * u;
      int r = q >> 3, k4 = (q & 7) * 4;
      float4 v = *(const float4*)(W + (size_t)(colBase + r) * D + kb + k4);
      Bs[r][k4 + 0] = v.x; Bs[r][k4 + 1] = v.y; Bs[r][k4 + 2] = v.z; Bs[r][k4 + 3] = v.w;
    }
    __syncthreads();
#pragma unroll 8
    for (int kk = 0; kk < 32; ++kk) {
      float b0 = Bs[tx * 4 + 0][kk], b1 = Bs[tx * 4 + 1][kk];
      float b2 = Bs[tx * 4 + 2][kk], b3 = Bs[tx * 4 + 3][kk];
#pragma unroll
      for (int i = 0; i < 2; ++i) {
        float a = As[ty * 2 + i][kk];
        acc[i][0] = fmaf(a, b0, acc[i][0]);
        acc[i][1] = fmaf(a, b1, acc[i][1]);
        acc[i][2] = fmaf(a, b2, acc[i][2]);
        acc[i][3] = fmaf(a, b3, acc[i][3]);
      }
    }
    __syncthreads();
  }
#pragma unroll
  for (int i = 0; i < 2; ++i) {
    int m = rowBase + ty * 2 + i;
#pragma unroll
    for (int j = 0; j < 4; ++j) {
      int n = colBase + tx * 4 + j;
      C[(size_t)m * D + n] = acc[i][j] + bias[n];
    }
  }
}

// ---------------- LayerNorm + exact GELU (in place) ------------------------

__global__ __launch_bounds__(256) void ln_gelu_kernel(float* __restrict__ h,
                                                      const float* __restrict__ g,
                                                      const float* __restrict__ b) {
  __shared__ float sbuf[4];
  int row = blockIdx.x, t = threadIdx.x;
  float* p = h + (size_t)row * D + t * 4;
  float4 x = *(float4*)p;
  float s = x.x + x.y + x.z + x.w;
  s = blockReduceSum(s, sbuf);
  float mu = s * (1.0f / D);
  float dx = x.x - mu, dy = x.y - mu, dz = x.z - mu, dw = x.w - mu;
  float ss = dx * dx + dy * dy + dz * dz + dw * dw;
  ss = blockReduceSum(ss, sbuf);
  float rstd = rsqrtf(ss * (1.0f / D) + 1e-5f);
  float4 gg = *(const float4*)(g + t * 4);
  float4 bb = *(const float4*)(b + t * 4);
  float y0 = dx * rstd * gg.x + bb.x;
  float y1 = dy * rstd * gg.y + bb.y;
  float y2 = dz * rstd * gg.z + bb.z;
  float y3 = dw * rstd * gg.w + bb.w;
  const float c = 0.70710678118654752f;
  y0 = 0.5f * y0 * (1.0f + erff(y0 * c));
  y1 = 0.5f * y1 * (1.0f + erff(y1 * c));
  y2 = 0.5f * y2 * (1.0f + erff(y2 * c));
  y3 = 0.5f * y3 * (1.0f + erff(y3 * c));
  *(float4*)p = make_float4(y0, y1, y2, y3);
}

// ---------------- L2 normalize rows of r; write in place + d_out -----------

__global__ __launch_bounds__(256) void l2norm_kernel(float* __restrict__ r,
                                                     float* __restrict__ outRef) {
  __shared__ float sbuf[4];
  int row = blockIdx.x, t = threadIdx.x;
  float* p = r + (size_t)row * D + t * 4;
  float4 x = *(float4*)p;
  float ss = x.x * x.x + x.y * x.y + x.z * x.z + x.w * x.w;
  ss = blockReduceSum(ss, sbuf);
  float inv = 1.0f / fmaxf(sqrtf(ss), 1e-12f);
  x.x *= inv; x.y *= inv; x.z *= inv; x.w *= inv;
  *(float4*)p = x;
  *(float4*)(outRef + (size_t)row * D + t * 4) = x;
}

// ---------------- A-prep: split refined into f16 hi/lo fragment layout -----
// Layout (bytes): [kb 0..32) * 32768 + (mt*2+half)*1024 + fraglane*16
// fraglane l holds rows mt*16+(l&15), k = kb*32 + (l>>4)*8 .. +8

__global__ __launch_bounds__(256) void aprep_kernel(const float* __restrict__ r,
                                                    float* __restrict__ Af) {
  int g = blockIdx.x * 256 + threadIdx.x;   // 32768 total
  int l = g & 63, mt = (g >> 6) & 15, kb = g >> 10;
  int row = mt * 16 + (l & 15);
  int k0 = kb * 32 + ((l >> 4) << 3);
  const float* src = r + (size_t)row * D + k0;
  union { float4 f; __half h[8]; } ph, pl;
#pragma unroll
  for (int e = 0; e < 8; ++e) {
    float x = src[e];
    __half hh = __float2half(x);
    ph.h[e] = hh;
    pl.h[e] = __float2half((x - __half2float(hh)) * 2048.0f);
  }
  float4* dst = (float4*)(Af + (size_t)kb * 8192 + mt * 512);
  dst[l] = ph.f;          // hi block
  dst[64 + l] = pl.f;     // lo block (+1024 bytes)
}

// ---------------- sims MFMA GEMM + fused row norms + per-row top-16 --------
// Block: 256 threads = 4 waves; wave w owns query rows [64w,64w+64).
// Per block: 4 subtiles of 64 memory rows; K=1024 in 32 steps of 32.
// S = Ah*Bh + 2^-11*(Ah*Bl' + Al'*Bh), f16 operands, fp32 accum.

__global__ __launch_bounds__(256, 2) void sims_topk_kernel(
    const float* __restrict__ Afrag, const float* __restrict__ mem,
    float* __restrict__ invn, float* __restrict__ cand_v,
    int* __restrict__ cand_i) {
  __shared__ __align__(16) char smem[66816];
  float* sInv = (float*)(smem + 66560);
  const int t = threadIdx.x;
  const int w = t >> 6, l = t & 63;
  const int nbase = blockIdx.x * CH;

  float tv[16];
  int ti[16];
#pragma unroll
  for (int s = 0; s < 16; ++s) { tv[s] = -FLT_MAX; ti[s] = 2147483647; }
  float curMin = -FLT_MAX;

  // B staging assignment (constant across subtiles/k-steps)
  const int n_loc = t >> 2;            // 0..63 row within subtile
  const int kseg = t & 3;              // 8-elem k-slice
  const int lp = (l & 3) * 16 + (l >> 2);  // fragment lane slot
  char* bdst_h = smem + 32768 + (w * 2 + 0) * 1024 + lp * 16;
  char* bdst_l = bdst_h + 1024;

  for (int sub = 0; sub < 4; ++sub) {
    const int n0 = nbase + sub * 64;
    const int nrow = n0 + n_loc;
    const bool vld = nrow < NMEM;
    const float* bsrc = mem + (size_t)nrow * D + kseg * 8;
    f32x4 acc1[4][4], acc2[4][4];
#pragma unroll
    for (int mi = 0; mi < 4; ++mi)
#pragma unroll
      for (int ni = 0; ni < 4; ++ni) { acc1[mi][ni] = 0.f; acc2[mi][ni] = 0.f; }
    float ssq = 0.f;

    for (int kb = 0; kb < 32; ++kb) {
      __syncthreads();
      // ---- stage A: 8 KB per wave, lane-linear direct-to-LDS
      {
        const char* asrc = (const char*)Afrag + (size_t)kb * 32768 + w * 8192;
        char* adst = smem + w * 8192;
#pragma unroll
        for (int u = 0; u < 8; ++u)
          async_copy16(asrc + u * 1024 + l * 16, adst + u * 1024);
      }
      // ---- stage B: reg-load fp32, split f16 hi / scaled-lo, sumsq
      {
        float4 v0 = make_float4(0.f, 0.f, 0.f, 0.f);
        float4 v1 = make_float4(0.f, 0.f, 0.f, 0.f);
        if (vld) {
          v0 = *(const float4*)(bsrc + kb * 32);
          v1 = *(const float4*)(bsrc + kb * 32 + 4);
        }
        ssq += v0.x * v0.x + v0.y * v0.y + v0.z * v0.z + v0.w * v0.w +
               v1.x * v1.x + v1.y * v1.y + v1.z * v1.z + v1.w * v1.w;
        float xs[8] = {v0.x, v0.y, v0.z, v0.w, v1.x, v1.y, v1.z, v1.w};
        union { s16x8 v; __half h[8]; } ph, pl;
#pragma unroll
        for (int e = 0; e < 8; ++e) {
          __half hh = __float2half(xs[e]);
          ph.h[e] = hh;
          pl.h[e] = __float2half((xs[e] - __half2float(hh)) * 2048.0f);
        }
        *(s16x8*)bdst_h = ph.v;
        *(s16x8*)bdst_l = pl.v;
      }
      __syncthreads();
      // ---- fragments + MFMA
      s16x8 ah[4], al[4];
#pragma unroll
      for (int mi = 0; mi < 4; ++mi) {
        const char* ab = smem + ((4 * w + mi) * 2) * 1024 + l * 16;
        ah[mi] = *(const s16x8*)(ab);
        al[mi] = *(const s16x8*)(ab + 1024);
      }
#pragma unroll
      for (int ni = 0; ni < 4; ++ni) {
        const char* bb = smem + 32768 + (ni * 2) * 1024 + l * 16;
        s16x8 bh = *(const s16x8*)(bb);
        s16x8 bl = *(const s16x8*)(bb + 1024);
#pragma unroll
        for (int mi = 0; mi < 4; ++mi) {
          mfma16(acc1[mi][ni], ah[mi], bh);
          mfma16(acc2[mi][ni], ah[mi], bl);
          mfma16(acc2[mi][ni], al[mi], bh);
        }
      }
    }
    // ---- row inverse norms (reduce over the 4 k-slices = lanes l^1, l^2)
    float s2 = ssq + __shfl_xor(ssq, 1, 64);
    s2 = s2 + __shfl_xor(s2, 2, 64);
    float inv = 1.0f / fmaxf(sqrtf(s2), 1e-12f);
    if (kseg == 0) {
      sInv[n_loc] = inv;
      if (vld) invn[nrow] = inv;
    }
    __syncthreads();
    // ---- dump S (combined) to wave-local LDS region, stride 65
    float* Sw = (float*)smem + w * 4160;
    const int rbase = (l >> 4) << 2, cbase = l & 15;
#pragma unroll
    for (int mi = 0; mi < 4; ++mi)
#pragma unroll
      for (int ni = 0; ni < 4; ++ni)
#pragma unroll
        for (int j = 0; j < 4; ++j)
          Sw[(mi * 16 + rbase + j) * 65 + ni * 16 + cbase] =
              acc1[mi][ni][j] + acc2[mi][ni][j] * (1.0f / 2048.0f);
    __syncthreads();
    // ---- scan: lane l owns global query row w*64+l == t
    const float* Sr = (float*)smem + w * 4160 + l * 65;
#pragma unroll 8
    for (int c = 0; c < 64; ++c) {
      int n = n0 + c;
      float v = Sr[c] * sInv[c];
      if (n < NMEM && v > curMin) {
        int ms = 0;
        float mv = tv[0];
#pragma unroll
        for (int s = 1; s < 16; ++s)
          if (tv[s] < mv) { mv = tv[s]; ms = s; }
#pragma unroll
        for (int s = 0; s < 16; ++s)
          if (s == ms) { tv[s] = v; ti[s] = n; }
        curMin = tv[0];
#pragma unroll
        for (int s = 1; s < 16; ++s) curMin = fminf(curMin, tv[s]);
      }
    }
    __syncthreads();
  }
  // thread t == query row t
  float* cv = cand_v + (size_t)t * CAND + (size_t)blockIdx.x * 16;
  int* ci = cand_i + (size_t)t * CAND + (size_t)blockIdx.x * 16;
#pragma unroll
  for (int s = 0; s < 16; ++s) { cv[s] = tv[s]; ci[s] = ti[s]; }
}

// ---------------- merge per-chunk top-16s (tie-aware, stable) --------------

__global__ __launch_bounds__(256) void topk_merge_kernel(
    const float* __restrict__ cand_v, const int* __restrict__ cand_i,
    float* __restrict__ out_vals, float* __restrict__ out_idx) {
  __shared__ float rv[256];
  __shared__ int ri[256];
  int b = blockIdx.x, t = threadIdx.x;
  const float* cv = cand_v + (size_t)b * CAND;
  const int* ci = cand_i + (size_t)b * CAND;
  float lastV = FLT_MAX;
  int lastI = -1;
  for (int pass = 0; pass < TOPK; ++pass) {
    float bv = -FLT_MAX;
    int bi = 2147483647;
    for (int p = t; p < CAND; p += 256) {
      float v = cv[p];
      int idx = ci[p];
      bool qual = (v < lastV) || (v == lastV && idx > lastI);
      bool better = (v > bv) || (v == bv && idx < bi);
      if (qual && better) { bv = v; bi = idx; }
    }
    rv[t] = bv; ri[t] = bi;
    __syncthreads();
    for (int off = 128; off > 0; off >>= 1) {
      if (t < off) {
        float v2 = rv[t + off];
        int i2 = ri[t + off];
        if (v2 > rv[t] || (v2 == rv[t] && i2 < ri[t])) { rv[t] = v2; ri[t] = i2; }
      }
      __syncthreads();
    }
    lastV = rv[0];
    lastI = ri[0];
    if (t == 0) {
      out_vals[b * TOPK + pass] = lastV;
      out_idx[b * TOPK + pass] = (float)lastI;
    }
    __syncthreads();
  }
}

// ---------------- gather retrieved = mem_n[topk_idx] -----------------------

__global__ __launch_bounds__(256) void gather_kernel(
    const float* __restrict__ out_idx, const float* __restrict__ mem,
    const float* __restrict__ invn, float* __restrict__ out_retr) {
  int p = blockIdx.x;  // 0..4095 = b*16+j
  int idx = (int)out_idx[p];
  float inv = invn[idx];
  int c = threadIdx.x * 4;
  float4 v = *(const float4*)(mem + (size_t)idx * D + c);
  v.x *= inv; v.y *= inv; v.z *= inv; v.w *= inv;
  *(float4*)(out_retr + (size_t)p * D + c) = v;
}

// ---------------- launch ---------------------------------------------------

extern "C" void kernel_launch(void* const* d_in, const int* in_sizes, int n_in,
                              void* d_out, int out_size, void* d_ws, size_t ws_size,
                              hipStream_t stream) {
  const float* query = (const float*)d_in[0];
  const float* W1 = (const float*)d_in[1];
  const float* b1 = (const float*)d_in[2];
  const float* ln_g = (const float*)d_in[3];
  const float* ln_b = (const float*)d_in[4];
  const float* W2 = (const float*)d_in[5];
  const float* b2 = (const float*)d_in[6];
  const float* mem = (const float*)d_in[7];

  float* out = (float*)d_out;
  float* out_refined = out;                    // 262144
  float* out_vals = out + 262144;              // 4096
  float* out_idx = out + 262144 + 4096;        // 4096
  float* out_retr = out + 262144 + 8192;       // 256*16*1024

  float* wsp = (float*)d_ws;
  float* h = wsp;                              // 262144
  float* r = wsp + 262144;                     // 262144
  float* invn = wsp + 524288;                  // 100352
  float* Af = wsp + 624640;                    // 262144 (1 MB f16 frag layout)
  float* cand_v = wsp + 886784;                // 1601536
  int* cand_i = (int*)(wsp + 2488320);         // 1601536; end 4089856

  gemm_bias_kernel<<<dim3(16, 8), 256, 0, stream>>>(query, W1, b1, h);
  ln_gelu_kernel<<<BQ, 256, 0, stream>>>(h, ln_g, ln_b);
  gemm_bias_kernel<<<dim3(16, 8), 256, 0, stream>>>(h, W2, b2, r);
  l2norm_kernel<<<BQ, 256, 0, stream>>>(r, out_refined);
  aprep_kernel<<<128, 256, 0, stream>>>(r, Af);
  sims_topk_kernel<<<NCHUNK, 256, 0, stream>>>(Af, mem, invn, cand_v, cand_i);
  topk_merge_kernel<<<BQ, 256, 0, stream>>>(cand_v, cand_i, out_vals, out_idx);
  gather_kernel<<<BQ * TOPK, 256, 0, stream>>>(out_idx, mem, invn, out_retr);
}

// Round 3
// 556.345 us; speedup vs baseline: 3.0564x; 1.0187x over previous
//
#include <hip/hip_runtime.h>
#include <hip/hip_fp16.h>
#include <float.h>
#include <math.h>

#define D 1024
#define BQ 256
#define NMEM 100000
#define TOPK 16
#define SIMS_BLOCKS 512
#define NTILES 1564              // 64-col tiles covering 100096 cols
#define CAND (SIMS_BLOCKS * TOPK) // 8192 candidates per query row

typedef __attribute__((ext_vector_type(4))) float f32x4;
typedef __attribute__((ext_vector_type(8))) short s16x8;

__device__ __forceinline__ void mfma16(f32x4& d, s16x8 a, s16x8 b) {
  asm("v_mfma_f32_16x16x32_f16 %0, %1, %2, %0" : "+v"(d) : "v"(a), "v"(b));
}

// ---------------- reductions ----------------

__device__ __forceinline__ float waveReduceSum(float v) {
#pragma unroll
  for (int o = 32; o > 0; o >>= 1) v += __shfl_xor(v, o, 64);
  return v;
}

__device__ __forceinline__ float blockReduceSum(float v, float* sbuf) {
  v = waveReduceSum(v);
  int w = threadIdx.x >> 6;
  if ((threadIdx.x & 63) == 0) sbuf[w] = v;
  __syncthreads();
  float r = sbuf[0] + sbuf[1] + sbuf[2] + sbuf[3];
  __syncthreads();
  return r;
}

// ---------------- prep: split [R][1024] f32 into f16 hi/lo fragment layout --
// dst bytes: kb*(R16*2048) + mt*2048 + {hi:0, lo:1024} + lane*16
// lane l <-> row mt*16+(l&15), k = kb*32 + (l>>4)*8 .. +8

__global__ __launch_bounds__(256) void prep_kernel(const float* __restrict__ src,
                                                   float* __restrict__ dst,
                                                   int R16) {
  int g = blockIdx.x * 256 + threadIdx.x;
  int l = g & 63;
  int mt = (g >> 6) % R16;
  int kb = (g >> 6) / R16;
  int row = mt * 16 + (l & 15);
  int k0 = kb * 32 + ((l >> 4) << 3);
  const float* s = src + (size_t)row * D + k0;
  float4 v0 = *(const float4*)(s);
  float4 v1 = *(const float4*)(s + 4);
  float xs[8] = {v0.x, v0.y, v0.z, v0.w, v1.x, v1.y, v1.z, v1.w};
  union { float4 f; __half h[8]; } ph, pl;
#pragma unroll
  for (int e = 0; e < 8; ++e) {
    float x = xs[e];
    __half hh = __float2half(x);
    ph.h[e] = hh;
    pl.h[e] = __float2half((x - __half2float(hh)) * 2048.0f);
  }
  char* db = (char*)dst + (size_t)kb * R16 * 2048 + mt * 2048 + l * 16;
  *(float4*)db = ph.f;
  *(float4*)(db + 1024) = pl.f;
}

// ---------------- MFMA projection GEMM: part[kc] = A @ W^T (K-chunked) -----
// Block = (ct 0..63 col-tile of 16, kc 0..3 K-chunk of 256). No LDS/barriers.

__global__ __launch_bounds__(256) void mfma_gemm_kernel(
    const float* __restrict__ Afr, const float* __restrict__ Wfr,
    float* __restrict__ part) {
  int t = threadIdx.x;
  int w = t >> 6, l = t & 63;
  int ct = blockIdx.x & 63;
  int kc = blockIdx.x >> 6;
  f32x4 acc1[4], acc2[4];
  f32x4 zz = {0.f, 0.f, 0.f, 0.f};
#pragma unroll
  for (int mi = 0; mi < 4; ++mi) { acc1[mi] = zz; acc2[mi] = zz; }
  const char* ab0 = (const char*)Afr + w * 8192 + l * 16;
  const char* bb0 = (const char*)Wfr + ct * 2048 + l * 16;
#pragma unroll 2
  for (int s = 0; s < 8; ++s) {
    int kb = kc * 8 + s;
    const char* bb = bb0 + (size_t)kb * 131072;
    s16x8 bh = *(const s16x8*)(bb);
    s16x8 bl = *(const s16x8*)(bb + 1024);
    const char* ab = ab0 + (size_t)kb * 32768;
#pragma unroll
    for (int mi = 0; mi < 4; ++mi) {
      s16x8 ah = *(const s16x8*)(ab + mi * 2048);
      s16x8 al = *(const s16x8*)(ab + mi * 2048 + 1024);
      mfma16(acc1[mi], ah, bh);
      mfma16(acc2[mi], ah, bl);
      mfma16(acc2[mi], al, bh);
    }
  }
  float* pb = part + (size_t)kc * 262144 + ct * 16 + (l & 15);
#pragma unroll
  for (int mi = 0; mi < 4; ++mi)
#pragma unroll
    for (int j = 0; j < 4; ++j) {
      int row = w * 64 + mi * 16 + ((l >> 4) << 2) + j;
      pb[(size_t)row * 1024] = acc1[mi][j] + acc2[mi][j] * (1.0f / 2048.0f);
    }
}

// ---------------- reduce partials + bias + LayerNorm + exact GELU ----------

__global__ __launch_bounds__(256) void reduce_ln_gelu_kernel(
    const float* __restrict__ part, const float* __restrict__ bias,
    const float* __restrict__ g, const float* __restrict__ b,
    float* __restrict__ h) {
  __shared__ float sbuf[4];
  int row = blockIdx.x, t = threadIdx.x;
  const float* p = part + (size_t)row * 1024 + t * 4;
  float4 x0 = *(const float4*)(p);
  float4 x1 = *(const float4*)(p + 262144);
  float4 x2 = *(const float4*)(p + 524288);
  float4 x3 = *(const float4*)(p + 786432);
  float4 bb = *(const float4*)(bias + t * 4);
  float vx = x0.x + x1.x + x2.x + x3.x + bb.x;
  float vy = x0.y + x1.y + x2.y + x3.y + bb.y;
  float vz = x0.z + x1.z + x2.z + x3.z + bb.z;
  float vw = x0.w + x1.w + x2.w + x3.w + bb.w;
  float s = blockReduceSum(vx + vy + vz + vw, sbuf);
  float mu = s * (1.0f / D);
  float dx = vx - mu, dy = vy - mu, dz = vz - mu, dw = vw - mu;
  float ss = blockReduceSum(dx * dx + dy * dy + dz * dz + dw * dw, sbuf);
  float rstd = rsqrtf(ss * (1.0f / D) + 1e-5f);
  float4 gg = *(const float4*)(g + t * 4);
  float4 be = *(const float4*)(b + t * 4);
  float y0 = dx * rstd * gg.x + be.x;
  float y1 = dy * rstd * gg.y + be.y;
  float y2 = dz * rstd * gg.z + be.z;
  float y3 = dw * rstd * gg.w + be.w;
  const float c = 0.70710678118654752f;
  y0 = 0.5f * y0 * (1.0f + erff(y0 * c));
  y1 = 0.5f * y1 * (1.0f + erff(y1 * c));
  y2 = 0.5f * y2 * (1.0f + erff(y2 * c));
  y3 = 0.5f * y3 * (1.0f + erff(y3 * c));
  *(float4*)(h + (size_t)row * D + t * 4) = make_float4(y0, y1, y2, y3);
}

// ---------------- reduce partials + bias + L2 normalize --------------------

__global__ __launch_bounds__(256) void reduce_l2norm_kernel(
    const float* __restrict__ part, const float* __restrict__ bias,
    float* __restrict__ r, float* __restrict__ outRef) {
  __shared__ float sbuf[4];
  int row = blockIdx.x, t = threadIdx.x;
  const float* p = part + (size_t)row * 1024 + t * 4;
  float4 x0 = *(const float4*)(p);
  float4 x1 = *(const float4*)(p + 262144);
  float4 x2 = *(const float4*)(p + 524288);
  float4 x3 = *(const float4*)(p + 786432);
  float4 bb = *(const float4*)(bias + t * 4);
  float vx = x0.x + x1.x + x2.x + x3.x + bb.x;
  float vy = x0.y + x1.y + x2.y + x3.y + bb.y;
  float vz = x0.z + x1.z + x2.z + x3.z + bb.z;
  float vw = x0.w + x1.w + x2.w + x3.w + bb.w;
  float ss = blockReduceSum(vx * vx + vy * vy + vz * vz + vw * vw, sbuf);
  float inv = 1.0f / fmaxf(sqrtf(ss), 1e-12f);
  float4 y = make_float4(vx * inv, vy * inv, vz * inv, vw * inv);
  *(float4*)(r + (size_t)row * D + t * 4) = y;
  *(float4*)(outRef + (size_t)row * D + t * 4) = y;
}

// ---------------- sims MFMA GEMM + fused row norms + per-row top-16 --------
// 512 blocks, 4 waves. Per 64-col tile: K=1024 in 32 steps, ONE raw barrier
// per step, B raw prefetched 1 step ahead (regs), B hi/lo LDS double-buffered,
// A-frags direct from L2-resident global (prefetched 1 step ahead).
// LDS: [0,16K) B dbuf (+sInv at 8K), [16K,80K) swizzled S[256][64].

#define KSTEP(KB, B0C, B1C, AHC, ALC, B0N, B1N, AHN, ALN)                      \
  do {                                                                         \
    const int kb_ = (KB);                                                      \
    const int kn_ = (kb_ + 1) & 31;                                            \
    union { s16x8 v; __half h[8]; } ph_, pl_;                                  \
    float xs_[8] = {B0C.x, B0C.y, B0C.z, B0C.w, B1C.x, B1C.y, B1C.z, B1C.w};   \
    _Pragma("unroll") for (int e = 0; e < 8; ++e) {                            \
      float x_ = xs_[e];                                                       \
      __half hh_ = __float2half(x_);                                           \
      ph_.h[e] = hh_;                                                          \
      pl_.h[e] = __float2half((x_ - __half2float(hh_)) * 2048.0f);             \
      ssq = fmaf(x_, x_, ssq);                                                 \
    }                                                                          \
    char* bw_ = smem + (kb_ & 1) * 8192 + bwroff;                              \
    *(s16x8*)bw_ = ph_.v;                                                      \
    *(s16x8*)(bw_ + 1024) = pl_.v;                                             \
    if (vld) {                                                                 \
      B0N = *(const float4*)(bsrc + kn_ * 32);                                 \
      B1N = *(const float4*)(bsrc + kn_ * 32 + 4);                             \
    }                                                                          \
    _Pragma("unroll") for (int mi = 0; mi < 4; ++mi) {                         \
      const char* ab_ = afb + (size_t)kn_ * 32768 + mi * 2048;                 \
      AHN[mi] = *(const s16x8*)(ab_);                                          \
      ALN[mi] = *(const s16x8*)(ab_ + 1024);                                   \
    }                                                                          \
    asm volatile("s_waitcnt lgkmcnt(0)\ns_barrier" ::: "memory");              \
    const char* bb_ = smem + (kb_ & 1) * 8192;                                 \
    __builtin_amdgcn_s_setprio(1);                                             \
    _Pragma("unroll") for (int ni = 0; ni < 4; ++ni) {                         \
      s16x8 bh_ = *(const s16x8*)(bb_ + ni * 2048 + l * 16);                   \
      s16x8 bl_ = *(const s16x8*)(bb_ + ni * 2048 + 1024 + l * 16);            \
      _Pragma("unroll") for (int mi = 0; mi < 4; ++mi) {                       \
        mfma16(acc1[mi][ni], AHC[mi], bh_);                                    \
        mfma16(acc2[mi][ni], AHC[mi], bl_);                                    \
        mfma16(acc2[mi][ni], ALC[mi], bh_);                                    \
      }                                                                        \
    }                                                                          \
    __builtin_amdgcn_s_setprio(0);                                             \
  } while (0)

__global__ __launch_bounds__(256, 2) void sims_topk_kernel(
    const float* __restrict__ Afrag, const float* __restrict__ mem,
    float* __restrict__ invn, float* __restrict__ cand_v,
    int* __restrict__ cand_i) {
  __shared__ __align__(16) char smem[81920];
  const int t = threadIdx.x;
  const int w = t >> 6, l = t & 63;

  int tile0, ntiles;
  if (blockIdx.x < 28) { tile0 = blockIdx.x * 4; ntiles = 4; }
  else { tile0 = 112 + (blockIdx.x - 28) * 3; ntiles = 3; }

  float tv[16];
  int ti[16];
#pragma unroll
  for (int s = 0; s < 16; ++s) { tv[s] = -FLT_MAX; ti[s] = 2147483647; }
  float curMin = -FLT_MAX;

  const int n_loc = t >> 2;
  const int kseg = t & 3;
  const int bwroff = w * 2048 + ((l & 3) * 16 + (l >> 2)) * 16;
  const char* afb = (const char*)Afrag + w * 8192 + l * 16;
  float* sInvp = (float*)(smem + 8192);
  float* S = (float*)(smem + 16384);

  for (int tt = 0; tt < ntiles; ++tt) {
    const int n0 = (tile0 + tt) * 64;
    const int nrow = n0 + n_loc;
    const bool vld = nrow < NMEM;
    const float* bsrc = mem + (size_t)nrow * D + kseg * 8;

    f32x4 acc1[4][4], acc2[4][4];
    f32x4 zz = {0.f, 0.f, 0.f, 0.f};
#pragma unroll
    for (int mi = 0; mi < 4; ++mi)
#pragma unroll
      for (int ni = 0; ni < 4; ++ni) { acc1[mi][ni] = zz; acc2[mi][ni] = zz; }
    float ssq = 0.f;

    float4 b0A = make_float4(0.f, 0.f, 0.f, 0.f), b1A = b0A;
    float4 b0B = b0A, b1B = b0A;
    s16x8 ahA[4], alA[4], ahB[4], alB[4];
    if (vld) { b0A = *(const float4*)(bsrc); b1A = *(const float4*)(bsrc + 4); }
#pragma unroll
    for (int mi = 0; mi < 4; ++mi) {
      const char* ab = afb + mi * 2048;
      ahA[mi] = *(const s16x8*)(ab);
      alA[mi] = *(const s16x8*)(ab + 1024);
    }

    for (int kb = 0; kb < 32; kb += 2) {
      KSTEP(kb, b0A, b1A, ahA, alA, b0B, b1B, ahB, alB);
      KSTEP(kb + 1, b0B, b1B, ahB, alB, b0A, b1A, ahA, alA);
    }

    // row inverse norms (reduce across the 4 kseg lanes)
    float s2 = ssq + __shfl_xor(ssq, 1, 64);
    s2 = s2 + __shfl_xor(s2, 2, 64);
    float inv = 1.0f / fmaxf(sqrtf(s2), 1e-12f);
    __syncthreads();  // all frag reads done before sInv overwrites buf1
    if (kseg == 0) {
      sInvp[n_loc] = inv;
      if (vld) invn[nrow] = inv;
    }
    __syncthreads();
    // dump S swizzled: word = row*64 + (col ^ (row&31))
#pragma unroll
    for (int mi = 0; mi < 4; ++mi)
#pragma unroll
      for (int ni = 0; ni < 4; ++ni)
#pragma unroll
        for (int j = 0; j < 4; ++j) {
          int row = w * 64 + mi * 16 + ((l >> 4) << 2) + j;
          int col = ni * 16 + (l & 15);
          S[row * 64 + (col ^ (row & 31))] =
              acc1[mi][ni][j] + acc2[mi][ni][j] * (1.0f / 2048.0f);
        }
    __syncthreads();
    // scan: thread t owns query row t
    {
      const int rx = t & 31;
      const float* Srow = S + t * 64;
#pragma unroll 8
      for (int c = 0; c < 64; ++c) {
        float v = Srow[c ^ rx] * sInvp[c];
        int n = n0 + c;
        if (n < NMEM && v > curMin) {
          int ms = 0;
          float mv = tv[0];
#pragma unroll
          for (int s = 1; s < 16; ++s)
            if (tv[s] < mv) { mv = tv[s]; ms = s; }
#pragma unroll
          for (int s = 0; s < 16; ++s)
            if (s == ms) { tv[s] = v; ti[s] = n; }
          curMin = tv[0];
#pragma unroll
          for (int s = 1; s < 16; ++s) curMin = fminf(curMin, tv[s]);
        }
      }
    }
    // next tile's first barrier orders buf0 reuse; no barrier needed here
  }
  float* cv = cand_v + (size_t)t * CAND + (size_t)blockIdx.x * 16;
  int* ci = cand_i + (size_t)t * CAND + (size_t)blockIdx.x * 16;
#pragma unroll
  for (int s = 0; s < 16; ++s) { cv[s] = tv[s]; ci[s] = ti[s]; }
}

// ---------------- merge per-block top-16s (tie-aware, stable) --------------

__global__ __launch_bounds__(256) void topk_merge_kernel(
    const float* __restrict__ cand_v, const int* __restrict__ cand_i,
    float* __restrict__ out_vals, float* __restrict__ out_idx) {
  __shared__ float rv[256];
  __shared__ int ri[256];
  int b = blockIdx.x, t = threadIdx.x;
  const float* cv = cand_v + (size_t)b * CAND;
  const int* ci = cand_i + (size_t)b * CAND;
  float lastV = FLT_MAX;
  int lastI = -1;
  for (int pass = 0; pass < TOPK; ++pass) {
    float bv = -FLT_MAX;
    int bi = 2147483647;
    for (int p = t; p < CAND; p += 256) {
      float v = cv[p];
      int idx = ci[p];
      bool qual = (v < lastV) || (v == lastV && idx > lastI);
      bool better = (v > bv) || (v == bv && idx < bi);
      if (qual && better) { bv = v; bi = idx; }
    }
    rv[t] = bv; ri[t] = bi;
    __syncthreads();
    for (int off = 128; off > 0; off >>= 1) {
      if (t < off) {
        float v2 = rv[t + off];
        int i2 = ri[t + off];
        if (v2 > rv[t] || (v2 == rv[t] && i2 < ri[t])) { rv[t] = v2; ri[t] = i2; }
      }
      __syncthreads();
    }
    lastV = rv[0];
    lastI = ri[0];
    if (t == 0) {
      out_vals[b * TOPK + pass] = lastV;
      out_idx[b * TOPK + pass] = (float)lastI;
    }
    __syncthreads();
  }
}

// ---------------- gather retrieved = mem_n[topk_idx] -----------------------

__global__ __launch_bounds__(256) void gather_kernel(
    const float* __restrict__ out_idx, const float* __restrict__ mem,
    const float* __restrict__ invn, float* __restrict__ out_retr) {
  int p = blockIdx.x;
  int idx = (int)out_idx[p];
  float inv = invn[idx];
  int c = threadIdx.x * 4;
  float4 v = *(const float4*)(mem + (size_t)idx * D + c);
  v.x *= inv; v.y *= inv; v.z *= inv; v.w *= inv;
  *(float4*)(out_retr + (size_t)p * D + c) = v;
}

// ---------------- launch ---------------------------------------------------

extern "C" void kernel_launch(void* const* d_in, const int* in_sizes, int n_in,
                              void* d_out, int out_size, void* d_ws, size_t ws_size,
                              hipStream_t stream) {
  const float* query = (const float*)d_in[0];
  const float* W1 = (const float*)d_in[1];
  const float* b1 = (const float*)d_in[2];
  const float* ln_g = (const float*)d_in[3];
  const float* ln_b = (const float*)d_in[4];
  const float* W2 = (const float*)d_in[5];
  const float* b2 = (const float*)d_in[6];
  const float* mem = (const float*)d_in[7];

  float* out = (float*)d_out;
  float* out_refined = out;                    // 262144
  float* out_vals = out + 262144;              // 4096
  float* out_idx = out + 262144 + 4096;        // 4096
  float* out_retr = out + 262144 + 8192;       // 256*16*1024

  float* wsp = (float*)d_ws;
  float* h = wsp;                              // 262144
  float* r = wsp + 262144;                     // 262144
  float* invn = wsp + 524288;                  // 100352
  float* Qf = wsp + 624640;                    // 262144 (also Hf)
  float* Af = wsp + 886784;                    // 262144
  float* W1f = wsp + 1148928;                  // 1048576
  float* W2f = wsp + 2197504;                  // 1048576
  float* part = wsp + 3246080;                 // 1048576 (4x256x1024)
  float* cand_v = wsp + 4294656;               // 2097152
  int* cand_i = (int*)(wsp + 6391808);         // 2097152; end 8488960

  prep_kernel<<<128, 256, 0, stream>>>(query, Qf, 16);
  prep_kernel<<<512, 256, 0, stream>>>(W1, W1f, 64);
  prep_kernel<<<512, 256, 0, stream>>>(W2, W2f, 64);
  mfma_gemm_kernel<<<256, 256, 0, stream>>>(Qf, W1f, part);
  reduce_ln_gelu_kernel<<<256, 256, 0, stream>>>(part, b1, ln_g, ln_b, h);
  prep_kernel<<<128, 256, 0, stream>>>(h, Qf, 16);
  mfma_gemm_kernel<<<256, 256, 0, stream>>>(Qf, W2f, part);
  reduce_l2norm_kernel<<<256, 256, 0, stream>>>(part, b2, r, out_refined);
  prep_kernel<<<128, 256, 0, stream>>>(r, Af, 16);
  sims_topk_kernel<<<SIMS_BLOCKS, 256, 0, stream>>>(Af, mem, invn, cand_v, cand_i);
  topk_merge_kernel<<<BQ, 256, 0, stream>>>(cand_v, cand_i, out_vals, out_idx);
  gather_kernel<<<BQ * TOPK, 256, 0, stream>>>(out_idx, mem, invn, out_retr);
}